// Round 1
// baseline (1095.366 us; speedup 1.0000x reference)
//
#include <hip/hip_runtime.h>

#define N_ 256
#define L_ 4096
#define DM_ 2048
#define STEPF (1.0f / 4096.0f)
#define TT 2048  // time-tile per conv block

// ---------------- Phase 1: build discretized kernel K ----------------

// M = (step/2)*A ; E0 = I + M
__global__ __launch_bounds__(256) void k_base(const float* __restrict__ A,
                                              float* __restrict__ M,
                                              float* __restrict__ E0) {
    int idx = blockIdx.x * 256 + threadIdx.x;
    float m = A[idx] * (0.5f * STEPF);
    M[idx] = m;
    int r = idx >> 8, c = idx & 255;
    E0[idx] = m + (r == c ? 1.0f : 0.0f);
}

// C[i][j] = sum_k A[i][k]*B[k][j] (+ I if ADDI). A is N_xN_ (ld N_), B is N_ x m (ldb), C (ldc).
template <bool ADDI>
__global__ __launch_bounds__(256) void k_gemm(const float* __restrict__ A,
                                              const float* __restrict__ B,
                                              float* __restrict__ C,
                                              int m, int ldb, int ldc) {
    __shared__ float As[16][17];
    __shared__ float Bs[16][17];
    int tx = threadIdx.x, ty = threadIdx.y;
    int j = blockIdx.x * 16 + tx;
    int i = blockIdx.y * 16 + ty;
    float acc = 0.f;
    for (int kk = 0; kk < N_; kk += 16) {
        As[ty][tx] = A[i * N_ + kk + tx];
        Bs[ty][tx] = (j < m) ? B[(kk + ty) * ldb + j] : 0.f;
        __syncthreads();
#pragma unroll
        for (int k = 0; k < 16; ++k) acc += As[ty][k] * Bs[k][tx];
        __syncthreads();
    }
    if (j < m) C[i * ldc + j] = acc + ((ADDI && i == j) ? 1.0f : 0.0f);
}

// X[:,0] = Bbar = step * BL @ B
__global__ __launch_bounds__(256) void k_bbar(const float* __restrict__ BL,
                                              const float* __restrict__ Bv,
                                              float* __restrict__ X) {
    __shared__ float bs[N_];
    int i = threadIdx.x;
    bs[i] = Bv[i];
    __syncthreads();
    float s = 0.f;
    for (int k = 0; k < N_; ++k) s += BL[i * N_ + k] * bs[k];
    X[(size_t)i * L_] = STEPF * s;
}

// K[l] = C . X[:,l]
__global__ __launch_bounds__(256) void k_K(const float* __restrict__ Cv,
                                           const float* __restrict__ X,
                                           float* __restrict__ K) {
    __shared__ float cs[N_];
    int t = threadIdx.x;
    cs[t] = Cv[t];
    __syncthreads();
    int l = blockIdx.x * 256 + t;
    float s = 0.f;
    for (int i = 0; i < N_; ++i) s += cs[i] * X[(size_t)i * L_ + l];
    K[l] = s;
}

// ---------------- Phase 2: causal conv out = y*K + D*y ----------------

__device__ __forceinline__ float f4get(const float4& v, int k) {
    return k == 0 ? v.x : k == 1 ? v.y : k == 2 ? v.z : v.w;
}

__global__ __launch_bounds__(256) void k_conv(const float* __restrict__ y,
                                              const float* __restrict__ Kg,
                                              const float* __restrict__ Dp,
                                              float* __restrict__ out) {
    __shared__ __align__(16) float ys[TT + 256];  // zero-padded y window
    __shared__ __align__(16) float Ks[256];       // K chunk
    const int d = blockIdx.x;
    const int t0 = blockIdx.y * TT;
    const int tid = threadIdx.x;
    const int uA = 4 * tid;          // outputs t0+uA..+3
    const int uB = 1024 + 4 * tid;   // outputs t0+uB..+3
    const float* __restrict__ yd = y + (size_t)d * L_;

    float accA[4] = {0.f, 0.f, 0.f, 0.f};
    float accB[4] = {0.f, 0.f, 0.f, 0.f};

    const int lend = t0 + TT;
    for (int l0 = 0; l0 < lend; l0 += 256) {
        // stage K chunk and y window: ys[i] = yhat[t0 - l0 - 256 + i]
        Ks[tid] = Kg[l0 + tid];
        const int base = t0 - l0 - 256;
#pragma unroll
        for (int s = 0; s < (TT + 256) / 256; ++s) {
            int i = s * 256 + tid;
            int g = base + i;
            ys[i] = (g >= 0) ? yd[g] : 0.f;  // g < L_ guaranteed by construction
        }
        __syncthreads();

        const bool doB = (l0 <= t0 + uB + 3);
        const bool doA = (l0 <= t0 + uA + 3);
        if (doB) {
            // sliding windows: wX0 = ys[uX - v + 252 .. +3], wX1 = ys[uX - v + 256 .. +3]
            float4 a1 = *(const float4*)&ys[uA + 256];
            float4 b1 = *(const float4*)&ys[uB + 256];
            for (int v = 0; v < 256; v += 4) {
                float4 kq = *(const float4*)&Ks[v];
                float4 b0 = *(const float4*)&ys[uB - v + 252];
#pragma unroll
                for (int j = 0; j < 4; ++j) {
                    float kv = f4get(kq, j);
#pragma unroll
                    for (int r = 0; r < 4; ++r) {
                        int p = r - j + 4;  // 1..7
                        float yv = (p < 4) ? f4get(b0, p) : f4get(b1, p - 4);
                        accB[r] = fmaf(kv, yv, accB[r]);
                    }
                }
                b1 = b0;
                if (doA) {
                    float4 a0 = *(const float4*)&ys[uA - v + 252];
#pragma unroll
                    for (int j = 0; j < 4; ++j) {
                        float kv = f4get(kq, j);
#pragma unroll
                        for (int r = 0; r < 4; ++r) {
                            int p = r - j + 4;
                            float yv = (p < 4) ? f4get(a0, p) : f4get(a1, p - 4);
                            accA[r] = fmaf(kv, yv, accA[r]);
                        }
                    }
                    a1 = a0;
                }
            }
        }
        __syncthreads();
    }

    // epilogue: add D*y, store
    const float D0 = Dp[0];
    {
        int t = t0 + uA;
        float4 yv = *(const float4*)&yd[t];
        float4 o;
        o.x = accA[0] + D0 * yv.x;
        o.y = accA[1] + D0 * yv.y;
        o.z = accA[2] + D0 * yv.z;
        o.w = accA[3] + D0 * yv.w;
        *(float4*)&out[(size_t)d * L_ + t] = o;
    }
    {
        int t = t0 + uB;
        float4 yv = *(const float4*)&yd[t];
        float4 o;
        o.x = accB[0] + D0 * yv.x;
        o.y = accB[1] + D0 * yv.y;
        o.z = accB[2] + D0 * yv.z;
        o.w = accB[3] + D0 * yv.w;
        *(float4*)&out[(size_t)d * L_ + t] = o;
    }
}

// ---------------- host ----------------

extern "C" void kernel_launch(void* const* d_in, const int* in_sizes, int n_in,
                              void* d_out, int out_size, void* d_ws, size_t ws_size,
                              hipStream_t stream) {
    const float* y  = (const float*)d_in[0];
    const float* A  = (const float*)d_in[1];
    const float* Bv = (const float*)d_in[2];
    const float* Cv = (const float*)d_in[3];
    const float* Dp = (const float*)d_in[4];
    float* out = (float*)d_out;
    float* w = (float*)d_ws;

    float* M    = w;
    float* E0   = w + 65536;
    float* Ea   = w + 131072;
    float* Eb   = w + 196608;
    float* Abar = w + 262144;
    float* Pa   = w + 327680;
    float* Pb   = w + 393216;
    float* X    = w + 458752;                 // N_ x L_ row-major
    float* Kb   = w + 458752 + (size_t)N_ * L_;

    dim3 b16(16, 16);
    k_base<<<256, 256, 0, stream>>>(A, M, E0);
    // Neumann: BL = I + M + M^2 + M^3 + M^4 (|M| ~ 2.4e-4, truncation ~1e-18)
    k_gemm<true ><<<dim3(16, 16), b16, 0, stream>>>(M, E0, Ea, N_, N_, N_);   // E1
    k_gemm<true ><<<dim3(16, 16), b16, 0, stream>>>(M, Ea, Eb, N_, N_, N_);   // E2
    k_gemm<true ><<<dim3(16, 16), b16, 0, stream>>>(M, Eb, Ea, N_, N_, N_);   // E3 = BL
    k_gemm<false><<<dim3(16, 16), b16, 0, stream>>>(Ea, E0, Abar, N_, N_, N_); // Abar = BL@(I+M)
    k_bbar<<<1, 256, 0, stream>>>(Ea, Bv, X);                                  // X[:,0] = Bbar

    // doubling: X[:, m:2m] = P @ X[:, :m],  P := Abar^m
    const float* P = Abar;
    float* pp[2] = {Pa, Pb};
    int pi = 0;
    for (int m = 1; m < L_; m <<= 1) {
        k_gemm<false><<<dim3((m + 15) / 16, 16), b16, 0, stream>>>(P, X, X + m, m, L_, L_);
        if (2 * m < L_) {
            k_gemm<false><<<dim3(16, 16), b16, 0, stream>>>(P, P, pp[pi], N_, N_, N_);
            P = pp[pi];
            pi ^= 1;
        }
    }
    k_K<<<16, 256, 0, stream>>>(Cv, X, Kb);

    k_conv<<<dim3(DM_, L_ / TT), 256, 0, stream>>>(y, Kb, Dp, out);

    (void)in_sizes; (void)n_in; (void)out_size; (void)ws_size;
}

// Round 2
// 550.312 us; speedup vs baseline: 1.9904x; 1.9904x over previous
//
#include <hip/hip_runtime.h>

#define N_ 256
#define L_ 4096
#define DM_ 2048
#define STEPF (1.0f / 4096.0f)

typedef short bf16x8 __attribute__((ext_vector_type(8)));
typedef float f32x4 __attribute__((ext_vector_type(4)));
typedef unsigned int uint32;

// ---------------- Phase 1: build discretized kernel K ----------------

// M = (step/2)*A ; E0 = I + M
__global__ __launch_bounds__(256) void k_base(const float* __restrict__ A,
                                              float* __restrict__ M,
                                              float* __restrict__ E0) {
    int idx = blockIdx.x * 256 + threadIdx.x;
    float m = A[idx] * (0.5f * STEPF);
    M[idx] = m;
    int r = idx >> 8, c = idx & 255;
    E0[idx] = m + (r == c ? 1.0f : 0.0f);
}

// 64x64-tile f32 GEMM: C[i][j] = sum_k A[i][k]*B[k][j] (+I if ADDI), rows=256 fixed.
// blockIdx.z==1 selects the second (B2,C2,cols2) problem (same A) - used to fuse
// the power-squaring GEMM with the doubling-expansion GEMM in one launch.
template <bool ADDI>
__global__ __launch_bounds__(256) void k_gemm64(const float* __restrict__ A,
                                                const float* __restrict__ B, float* __restrict__ C,
                                                int cols, int ldb, int ldc,
                                                const float* __restrict__ B2, float* __restrict__ C2,
                                                int cols2, int ldb2, int ldc2) {
    const float* Bp = B; float* Cp = C; int m = cols, lb = ldb, lc = ldc;
    if (blockIdx.z) { Bp = B2; Cp = C2; m = cols2; lb = ldb2; lc = ldc2; }
    int bx = blockIdx.x, by = blockIdx.y;
    if (bx * 64 >= m) return;
    __shared__ float As[16][65];  // [k][i], padded
    __shared__ float Bs[16][68];  // [k][j], padded
    int tid = threadIdx.x;
    int tx = tid & 15, ty = tid >> 4;
    int row0 = by * 64, col0 = bx * 64;
    float acc[4][4] = {};
    for (int kk = 0; kk < 256; kk += 16) {
#pragma unroll
        for (int i = 0; i < 4; ++i)
            As[tx][ty * 4 + i] = A[(row0 + ty * 4 + i) * 256 + kk + tx];
#pragma unroll
        for (int i = 0; i < 4; ++i) {
            int j = tx + 16 * i;
            Bs[ty][j] = (col0 + j < m) ? Bp[(kk + ty) * lb + col0 + j] : 0.f;
        }
        __syncthreads();
#pragma unroll
        for (int k = 0; k < 16; ++k) {
            float a0 = As[k][ty * 4 + 0], a1 = As[k][ty * 4 + 1];
            float a2 = As[k][ty * 4 + 2], a3 = As[k][ty * 4 + 3];
            float b0 = Bs[k][tx * 4 + 0], b1 = Bs[k][tx * 4 + 1];
            float b2 = Bs[k][tx * 4 + 2], b3 = Bs[k][tx * 4 + 3];
            acc[0][0] = fmaf(a0, b0, acc[0][0]); acc[0][1] = fmaf(a0, b1, acc[0][1]);
            acc[0][2] = fmaf(a0, b2, acc[0][2]); acc[0][3] = fmaf(a0, b3, acc[0][3]);
            acc[1][0] = fmaf(a1, b0, acc[1][0]); acc[1][1] = fmaf(a1, b1, acc[1][1]);
            acc[1][2] = fmaf(a1, b2, acc[1][2]); acc[1][3] = fmaf(a1, b3, acc[1][3]);
            acc[2][0] = fmaf(a2, b0, acc[2][0]); acc[2][1] = fmaf(a2, b1, acc[2][1]);
            acc[2][2] = fmaf(a2, b2, acc[2][2]); acc[2][3] = fmaf(a2, b3, acc[2][3]);
            acc[3][0] = fmaf(a3, b0, acc[3][0]); acc[3][1] = fmaf(a3, b1, acc[3][1]);
            acc[3][2] = fmaf(a3, b2, acc[3][2]); acc[3][3] = fmaf(a3, b3, acc[3][3]);
        }
        __syncthreads();
    }
#pragma unroll
    for (int i = 0; i < 4; ++i) {
        int grow = row0 + ty * 4 + i;
#pragma unroll
        for (int j = 0; j < 4; ++j) {
            int gcol = col0 + tx * 4 + j;
            if (gcol < m) {
                float v = acc[i][j];
                if (ADDI && grow == gcol) v += 1.0f;
                Cp[grow * lc + gcol] = v;
            }
        }
    }
}

// X[:,0] = Bbar = step * BL @ B
__global__ __launch_bounds__(256) void k_bbar(const float* __restrict__ BL,
                                              const float* __restrict__ Bv,
                                              float* __restrict__ X) {
    __shared__ float bs[N_];
    int i = threadIdx.x;
    bs[i] = Bv[i];
    __syncthreads();
    float s = 0.f;
    for (int k = 0; k < N_; ++k) s += BL[i * N_ + k] * bs[k];
    X[(size_t)i * L_] = STEPF * s;
}

// K[l] = C . X[:,l]
__global__ __launch_bounds__(256) void k_K(const float* __restrict__ Cv,
                                           const float* __restrict__ X,
                                           float* __restrict__ K) {
    __shared__ float cs[N_];
    int t = threadIdx.x;
    cs[t] = Cv[t];
    __syncthreads();
    int l = blockIdx.x * 256 + t;
    float s = 0.f;
    for (int i = 0; i < N_; ++i) s += cs[i] * X[(size_t)i * L_ + l];
    K[l] = s;
}

// Pair-packed reversed K (bf16): R[i] = { lo16: K[4095-i], hi16: K[4094-i] }, 0 when OOB.
__device__ __forceinline__ uint32 bf16rne(float f) {
    uint32 u = __builtin_bit_cast(uint32, f);
    return (u + 0x7FFFu + ((u >> 16) & 1u)) >> 16;
}
__global__ __launch_bounds__(256) void k_pack(const float* __restrict__ Kf, uint32* __restrict__ R) {
    int i = blockIdx.x * 256 + threadIdx.x;   // grid 17*256 = 4352
    uint32 lo = 0, hi = 0;
    int a = 4095 - i;
    int b = 4094 - i;
    if (a >= 0) lo = bf16rne(Kf[a]);
    if (b >= 0) hi = bf16rne(Kf[b]);
    R[i] = lo | (hi << 16);
}

// ---------------- Phase 2: MFMA causal conv: out = y (*) K + D*y ----------------
// Out[d, t] = sum_j y[d, j] * K[t - j].  A-frag = y (bf16, per-lane 8 consecutive j),
// B-frag = Toeplitz K from pair-packed reversed LDS array (2x ds_read2_b32 per frag).
// Per wave: 1 d-tile (16) x 8 t-tiles (128 t), lag-1 frag reuse: frag(ti,s+1)==frag(ti-2,s).

__device__ __forceinline__ uint32 pk2(float lo, float hi) {  // truncate-pack 2 f32 -> 2 bf16
    return (__builtin_bit_cast(uint32, hi) & 0xFFFF0000u) | (__builtin_bit_cast(uint32, lo) >> 16);
}

__global__ __launch_bounds__(256, 4) void k_conv(const uint32* __restrict__ Rg,
                                                 const float* __restrict__ y,
                                                 const float* __restrict__ Dp,
                                                 float* __restrict__ out) {
    __shared__ uint32 Rl[4352];
    int tid = threadIdx.x;
#pragma unroll
    for (int i = 0; i < 17; ++i) Rl[i * 256 + tid] = Rg[i * 256 + tid];
    __syncthreads();

    const int w = tid >> 6, lane = tid & 63;
    const int n = lane & 15, g = lane >> 4;           // n: row/col within tile, g: k-group
    const int t0 = (31 - (int)blockIdx.x) * 128;      // reversed for load balance
    const int d0w = (int)blockIdx.y * 64 + w * 16;    // wave's 16-row d-tile
    const int d = d0w + n;                            // A-operand row for this lane
    const int nsteps = (t0 >> 5) + 4;                 // j-chunks of 32
    const float* __restrict__ yrow = y + (size_t)d * L_;
    const float4* __restrict__ yrow4 = (const float4*)yrow;

    // dword index base: frag(ti, s) reads Rl[base0 - 16*ti + 32*s + {0,2,4,6}]
    int base0 = 4095 - t0 - n + 8 * g;

    f32x4 acc[8];
#pragma unroll
    for (int i = 0; i < 8; ++i) acc[i] = (f32x4){0.f, 0.f, 0.f, 0.f};
    bf16x8 fr[8];
    bf16x8 av;

#define LOADF(SL, BI) { \
    uint32 r0 = Rl[(BI)], r1 = Rl[(BI) + 2], r2 = Rl[(BI) + 4], r3 = Rl[(BI) + 6]; \
    uint4 uu; uu.x = r0; uu.y = r1; uu.z = r2; uu.w = r3; \
    fr[SL] = __builtin_bit_cast(bf16x8, uu); }

#define LOADA(S) { \
    float4 q0 = yrow4[8 * (S) + 2 * g]; \
    float4 q1 = yrow4[8 * (S) + 2 * g + 1]; \
    uint4 ua; ua.x = pk2(q0.x, q0.y); ua.y = pk2(q0.z, q0.w); \
    ua.z = pk2(q1.x, q1.y); ua.w = pk2(q1.z, q1.w); \
    av = __builtin_bit_cast(bf16x8, ua); }

#define MF(TI, SL) acc[TI] = __builtin_amdgcn_mfma_f32_16x16x32_bf16(av, fr[SL], acc[TI], 0, 0, 0);

    // ---- step s = 0: fill all 8 slots (slot ti holds frag(ti, 0)) ----
    LOADA(0);
    LOADF(0, base0);       LOADF(1, base0 - 16);  LOADF(2, base0 - 32);  LOADF(3, base0 - 48);
    LOADF(4, base0 - 64);  LOADF(5, base0 - 80);  LOADF(6, base0 - 96);  LOADF(7, base0 - 112);
    MF(0, 0) MF(1, 1) MF(2, 2) MF(3, 3) MF(4, 4) MF(5, 5) MF(6, 6) MF(7, 7)

    int bcur = base0;

#define STEP(I, S0, S1, S2, S3, S4, S5, S6, S7) { \
    int s = sb + (I); \
    if (s < nsteps) { \
        bcur += 32; \
        LOADF(S0, bcur); \
        LOADF(S1, bcur - 16); \
        LOADA(s); \
        MF(0, S0) MF(1, S1) MF(2, S2) MF(3, S3) MF(4, S4) MF(5, S5) MF(6, S6) MF(7, S7) \
    } }

    for (int sb = 1; sb < nsteps; sb += 4) {
        STEP(0, 6, 7, 0, 1, 2, 3, 4, 5)
        STEP(1, 4, 5, 6, 7, 0, 1, 2, 3)
        STEP(2, 2, 3, 4, 5, 6, 7, 0, 1)
        STEP(3, 0, 1, 2, 3, 4, 5, 6, 7)
    }
#undef STEP
#undef MF
#undef LOADA
#undef LOADF

    // ---- epilogue: out = acc + D*y ----
    const float D0 = Dp[0];
#pragma unroll
    for (int ti = 0; ti < 8; ++ti) {
        int tcol = t0 + 16 * ti + n;
#pragma unroll
        for (int r = 0; r < 4; ++r) {
            int dr = d0w + 4 * g + r;
            size_t ix = (size_t)dr * L_ + tcol;
            out[ix] = acc[ti][r] + D0 * y[ix];
        }
    }
}

// ---------------- host ----------------

extern "C" void kernel_launch(void* const* d_in, const int* in_sizes, int n_in,
                              void* d_out, int out_size, void* d_ws, size_t ws_size,
                              hipStream_t stream) {
    const float* y  = (const float*)d_in[0];
    const float* A  = (const float*)d_in[1];
    const float* Bv = (const float*)d_in[2];
    const float* Cv = (const float*)d_in[3];
    const float* Dp = (const float*)d_in[4];
    float* out = (float*)d_out;
    float* w = (float*)d_ws;

    float* Mb   = w;                 // dead after E3; reused for R
    float* E0   = w + 65536;         // dead after Abar; reused for Kf
    float* Ea   = w + 131072;
    float* Eb   = w + 196608;
    float* Abar = w + 262144;
    float* Pa   = w + 327680;
    float* Pb   = w + 393216;
    float* X    = w + 458752;        // 256 x 4096 row-major
    float* Kf   = E0;                // K (f32)
    uint32* R   = (uint32*)Mb;       // 4352 pair-packed reversed bf16 K

    dim3 b256(256);
    k_base<<<dim3(256), b256, 0, stream>>>(A, Mb, E0);
    // Neumann: BL = I + M + M^2 + M^3 + M^4 (||M|| ~ 2.4e-4)
    k_gemm64<true ><<<dim3(4, 4, 1), b256, 0, stream>>>(Mb, E0, Ea, 256, 256, 256, nullptr, nullptr, 0, 256, 256); // E1
    k_gemm64<true ><<<dim3(4, 4, 1), b256, 0, stream>>>(Mb, Ea, Eb, 256, 256, 256, nullptr, nullptr, 0, 256, 256); // E2
    k_gemm64<true ><<<dim3(4, 4, 1), b256, 0, stream>>>(Mb, Eb, Ea, 256, 256, 256, nullptr, nullptr, 0, 256, 256); // E3 = BL
    k_gemm64<false><<<dim3(4, 4, 1), b256, 0, stream>>>(Ea, E0, Abar, 256, 256, 256, nullptr, nullptr, 0, 256, 256); // Abar
    k_bbar<<<dim3(1), b256, 0, stream>>>(Ea, Bv, X);

    // doubling: X[:, m:2m] = P @ X[:, :m]; fused with next-power squaring P' = P@P
    const float* P = Abar;
    float* pp[2] = {Pa, Pb};
    int pi = 0;
    for (int m = 1; m < L_; m <<= 1) {
        int gx = (m + 63) / 64;
        if (2 * m < L_) {
            k_gemm64<false><<<dim3(gx > 4 ? gx : 4, 4, 2), b256, 0, stream>>>(
                P, X, X + m, m, L_, L_, P, pp[pi], 256, 256, 256);
            P = pp[pi];
            pi ^= 1;
        } else {
            k_gemm64<false><<<dim3(gx, 4, 1), b256, 0, stream>>>(
                P, X, X + m, m, L_, L_, nullptr, nullptr, 0, 256, 256);
        }
    }
    k_K<<<dim3(16), b256, 0, stream>>>(Cv, X, Kf);
    k_pack<<<dim3(17), b256, 0, stream>>>(Kf, R);

    // conv: grid.x = t-block (reversed), grid.y = d-block (64 rows)
    k_conv<<<dim3(32, 32), b256, 0, stream>>>(R, y, Dp, out);

    (void)in_sizes; (void)n_in; (void)out_size; (void)ws_size;
}

// Round 3
// 214.953 us; speedup vs baseline: 5.0958x; 2.5601x over previous
//
#include <hip/hip_runtime.h>

#define N_ 256
#define L_ 4096
#define DM_ 2048
#define STEPF (1.0f / 4096.0f)
#define NW 22   // W-side Taylor terms: (0.984*||A||)^22/22! ~ 1e-14
#define NV 12   // V-side Taylor terms: (0.0154*||A||)^12/12! ~ 0

typedef short bf16x8 __attribute__((ext_vector_type(8)));
typedef float f32x4 __attribute__((ext_vector_type(4)));
typedef unsigned int uint32;

__device__ __forceinline__ uint32 bf16rne(float f) {
    uint32 u = __builtin_bit_cast(uint32, f);
    return (u + 0x7FFFu + ((u >> 16) & 1u)) >> 16;
}
__device__ __forceinline__ uint32 pk2(float lo, float hi) {  // truncate-pack 2 f32 -> 2 bf16
    return (__builtin_bit_cast(uint32, hi) & 0xFFFF0000u) | (__builtin_bit_cast(uint32, lo) >> 16);
}

// ---------------- Phase 1a: Krylov build of W (64x256) and V (256x64) ----------------
// S := ln(Abar) = step*A + O(M^3) (2.2e-8 rel, negligible).
// W[q,:] = C * exp(64q S) = sum_n vt_n * (q/63)^n,  vt_n = C (4032 S)^n / n!
// V[:,r] = exp(r S) * Bbar = sum_n ut_n * (r/63)^n, ut_n = (63 S)^n / n! * Bbar
// Bbar = (I-M)^-1 (step B) via 3-term Neumann (error ~1e-15).
__global__ __launch_bounds__(256) void k_kry(const float* __restrict__ Araw,
                                             const float* __restrict__ Bv,
                                             const float* __restrict__ Cv,
                                             float* __restrict__ W,
                                             float* __restrict__ V) {
    __shared__ float kry[NW][256];
    __shared__ float cur[256];
    const int j = threadIdx.x;
    if (blockIdx.x == 0) {
        // ---- W-side: row-vector Krylov. vt_n = (vt_{n-1} * A) * (4032*step/n) ----
        const float WSC = 4032.0f / 4096.0f;
        kry[0][j] = Cv[j];
        __syncthreads();
        for (int n = 1; n < NW; ++n) {
            float s0 = 0.f, s1 = 0.f, s2 = 0.f, s3 = 0.f;
            const float* __restrict__ Acol = Araw + j;   // column j, stride 256
            const float* __restrict__ kp = &kry[n - 1][0];
            for (int k = 0; k < 256; k += 4) {
                s0 = fmaf(kp[k],     Acol[(size_t)(k) * 256],     s0);
                s1 = fmaf(kp[k + 1], Acol[(size_t)(k + 1) * 256], s1);
                s2 = fmaf(kp[k + 2], Acol[(size_t)(k + 2) * 256], s2);
                s3 = fmaf(kp[k + 3], Acol[(size_t)(k + 3) * 256], s3);
            }
            kry[n][j] = ((s0 + s1) + (s2 + s3)) * (WSC / (float)n);
            __syncthreads();
        }
        float kj[NW];
#pragma unroll
        for (int n = 0; n < NW; ++n) kj[n] = kry[n][j];
        for (int q = 0; q < 64; ++q) {
            float c = (float)q * (1.0f / 63.0f);
            float h = kj[NW - 1];
#pragma unroll
            for (int n = NW - 2; n >= 0; --n) h = fmaf(c, h, kj[n]);
            W[q * 256 + j] = h;
        }
    } else {
        // ---- V-side: column Krylov. Bbar first (Neumann with M = (step/2) A). ----
        const float ms = 0.5f * STEPF;
        const float VSC = 63.0f / 4096.0f;
        cur[j] = Bv[j];
        __syncthreads();
        for (int it = 0; it < 3; ++it) {
            float s0 = 0.f, s1 = 0.f, s2 = 0.f, s3 = 0.f;
            const float4* __restrict__ Ar = (const float4*)(Araw + (size_t)j * 256);
            for (int k = 0; k < 64; ++k) {
                float4 a = Ar[k];
                s0 = fmaf(a.x, cur[4 * k],     s0);
                s1 = fmaf(a.y, cur[4 * k + 1], s1);
                s2 = fmaf(a.z, cur[4 * k + 2], s2);
                s3 = fmaf(a.w, cur[4 * k + 3], s3);
            }
            float nb = fmaf(ms, (s0 + s1) + (s2 + s3), Bv[j]);
            __syncthreads();
            cur[j] = nb;
            __syncthreads();
        }
        kry[0][j] = STEPF * cur[j];
        __syncthreads();
        for (int n = 1; n < NV; ++n) {
            float s0 = 0.f, s1 = 0.f, s2 = 0.f, s3 = 0.f;
            const float4* __restrict__ Ar = (const float4*)(Araw + (size_t)j * 256);
            const float* __restrict__ kp = &kry[n - 1][0];
            for (int k = 0; k < 64; ++k) {
                float4 a = Ar[k];
                s0 = fmaf(a.x, kp[4 * k],     s0);
                s1 = fmaf(a.y, kp[4 * k + 1], s1);
                s2 = fmaf(a.z, kp[4 * k + 2], s2);
                s3 = fmaf(a.w, kp[4 * k + 3], s3);
            }
            kry[n][j] = ((s0 + s1) + (s2 + s3)) * (VSC / (float)n);
            __syncthreads();
        }
        float kj[NV];
#pragma unroll
        for (int n = 0; n < NV; ++n) kj[n] = kry[n][j];
        for (int r4 = 0; r4 < 64; r4 += 4) {
            float4 o;
            float* op = (float*)&o;
#pragma unroll
            for (int u = 0; u < 4; ++u) {
                float c = (float)(r4 + u) * (1.0f / 63.0f);
                float h = kj[NV - 1];
#pragma unroll
                for (int n = NV - 2; n >= 0; --n) h = fmaf(c, h, kj[n]);
                op[u] = h;
            }
            *(float4*)(V + (size_t)j * 64 + r4) = o;
        }
    }
}

// ---------------- Phase 1b: small GEMM Kf = W * V  (Kf[64q + r] = K[l]) ----------------
__global__ __launch_bounds__(256) void k_g(const float* __restrict__ A, const float* __restrict__ B,
                                           float* __restrict__ C, int Ma, int Nb,
                                           int lda, int ldb, int ldc, float alpha, float diagv) {
    int row0 = blockIdx.y * 32, col0 = blockIdx.x * 32;
    if (row0 >= Ma || col0 >= Nb) return;
    __shared__ float As[16][33], Bs[16][33];
    int tid = threadIdx.x;
    int tx = tid & 15, ty = tid >> 4;
    int e0 = tid * 2, e1 = e0 + 1;
    int ai0 = e0 >> 4, ak0 = e0 & 15, ai1 = e1 >> 4, ak1 = e1 & 15;
    int bj0 = e0 & 31, bk0 = e0 >> 5, bj1 = e1 & 31, bk1 = e1 >> 5;
    bool va0 = (row0 + ai0) < Ma, va1 = (row0 + ai1) < Ma;
    bool vb0 = (col0 + bj0) < Nb, vb1 = (col0 + bj1) < Nb;
    float a0p = va0 ? A[(row0 + ai0) * lda + ak0] : 0.f;
    float a1p = va1 ? A[(row0 + ai1) * lda + ak1] : 0.f;
    float b0p = vb0 ? B[bk0 * ldb + col0 + bj0] : 0.f;
    float b1p = vb1 ? B[bk1 * ldb + col0 + bj1] : 0.f;
    float acc00 = 0.f, acc01 = 0.f, acc10 = 0.f, acc11 = 0.f;
    for (int kk = 0; kk < 256; kk += 16) {
        As[ak0][ai0] = a0p; As[ak1][ai1] = a1p;
        Bs[bk0][bj0] = b0p; Bs[bk1][bj1] = b1p;
        __syncthreads();
        if (kk + 16 < 256) {
            a0p = va0 ? A[(row0 + ai0) * lda + kk + 16 + ak0] : 0.f;
            a1p = va1 ? A[(row0 + ai1) * lda + kk + 16 + ak1] : 0.f;
            b0p = vb0 ? B[(bk0 + kk + 16) * ldb + col0 + bj0] : 0.f;
            b1p = vb1 ? B[(bk1 + kk + 16) * ldb + col0 + bj1] : 0.f;
        }
#pragma unroll
        for (int k = 0; k < 16; ++k) {
            float a0 = As[k][ty * 2], a1 = As[k][ty * 2 + 1];
            float b0 = Bs[k][tx * 2], b1 = Bs[k][tx * 2 + 1];
            acc00 = fmaf(a0, b0, acc00); acc01 = fmaf(a0, b1, acc01);
            acc10 = fmaf(a1, b0, acc10); acc11 = fmaf(a1, b1, acc11);
        }
        __syncthreads();
    }
    float accs[2][2] = {{acc00, acc01}, {acc10, acc11}};
#pragma unroll
    for (int i = 0; i < 2; ++i) {
        int r = row0 + ty * 2 + i;
        if (r < Ma)
#pragma unroll
            for (int jj = 0; jj < 2; ++jj) {
                int c = col0 + tx * 2 + jj;
                if (c < Nb) {
                    float v = alpha * accs[i][jj];
                    if (r == c) v += diagv;
                    C[r * ldc + c] = v;
                }
            }
    }
}

// ---------------- Phase 2: MFMA causal conv, software-pipelined ----------------
// Out[d,t] = sum_j y[d,j] K[t-j].  A-frag = y(bf16), B-frag = Toeplitz K from
// pair-packed reversed LDS array. Pipelining: next step's 8 LDS dwords + 2 y-float4
// prefetched into temps during current step's 8 MFMAs.
__global__ __launch_bounds__(256, 4) void k_conv(const float* __restrict__ Kf,
                                                 const float* __restrict__ y,
                                                 const float* __restrict__ Dp,
                                                 float* __restrict__ out) {
    __shared__ uint32 Rl[4352];
    const int tid = threadIdx.x;
#pragma unroll
    for (int i = 0; i < 17; ++i) {   // inline pack: Rl[i] = {K[4095-i], K[4094-i]} bf16
        int idx = i * 256 + tid;
        int a = 4095 - idx;
        uint32 lo = (a >= 0) ? bf16rne(Kf[a]) : 0u;
        uint32 hi = (a >= 1) ? bf16rne(Kf[a - 1]) : 0u;
        Rl[idx] = lo | (hi << 16);
    }
    __syncthreads();

    const int w = tid >> 6, lane = tid & 63;
    const int n = lane & 15, g = lane >> 4;
    const int t0 = (31 - (int)blockIdx.y) * 128;      // t-reversed: heavy blocks first
    const int d0w = (int)blockIdx.x * 64 + w * 16;    // d-major grid: XCD = dblk%8
    const int d = d0w + n;
    const int nsteps = (t0 >> 5) + 4;
    const float4* __restrict__ yrow4 = (const float4*)(y + (size_t)d * L_);
    int base0 = 4095 - t0 - n + 8 * g;

    f32x4 acc[8];
#pragma unroll
    for (int i = 0; i < 8; ++i) acc[i] = (f32x4){0.f, 0.f, 0.f, 0.f};
    bf16x8 fr[8], av;
    uint32 p0, p1, p2, p3, p4, p5, p6, p7;
    float4 pq0, pq1;

#define LOADF(SL, BI) { \
    uint4 uu; uu.x = Rl[(BI)]; uu.y = Rl[(BI) + 2]; uu.z = Rl[(BI) + 4]; uu.w = Rl[(BI) + 6]; \
    fr[SL] = __builtin_bit_cast(bf16x8, uu); }
#define PACKAV(Q0, Q1) { \
    uint4 ua; ua.x = pk2((Q0).x, (Q0).y); ua.y = pk2((Q0).z, (Q0).w); \
    ua.z = pk2((Q1).x, (Q1).y); ua.w = pk2((Q1).z, (Q1).w); \
    av = __builtin_bit_cast(bf16x8, ua); }
#define MF(TI, SL) acc[TI] = __builtin_amdgcn_mfma_f32_16x16x32_bf16(av, fr[SL], acc[TI], 0, 0, 0);

    // ---- prologue: step 0 + prefetch step 1 (nsteps >= 4 always) ----
    { float4 q0 = yrow4[2 * g], q1 = yrow4[2 * g + 1]; PACKAV(q0, q1); }
    LOADF(0, base0)       LOADF(1, base0 - 16)  LOADF(2, base0 - 32)  LOADF(3, base0 - 48)
    LOADF(4, base0 - 64)  LOADF(5, base0 - 80)  LOADF(6, base0 - 96)  LOADF(7, base0 - 112)
    p0 = Rl[base0 + 32]; p1 = Rl[base0 + 34]; p2 = Rl[base0 + 36]; p3 = Rl[base0 + 38];
    p4 = Rl[base0 + 16]; p5 = Rl[base0 + 18]; p6 = Rl[base0 + 20]; p7 = Rl[base0 + 22];
    pq0 = yrow4[8 + 2 * g]; pq1 = yrow4[8 + 2 * g + 1];
    MF(0, 0) MF(1, 1) MF(2, 2) MF(3, 3) MF(4, 4) MF(5, 5) MF(6, 6) MF(7, 7)

    int bcur = base0;

#define STEPP(I, S0, S1, S2, S3, S4, S5, S6, S7) { \
    const int s = sb + (I); \
    if (s < nsteps) { \
        { uint4 u0; u0.x = p0; u0.y = p1; u0.z = p2; u0.w = p3; fr[S0] = __builtin_bit_cast(bf16x8, u0); } \
        { uint4 u1; u1.x = p4; u1.y = p5; u1.z = p6; u1.w = p7; fr[S1] = __builtin_bit_cast(bf16x8, u1); } \
        PACKAV(pq0, pq1); \
        bcur += 32; \
        if (s + 1 < nsteps) { \
            p0 = Rl[bcur + 32]; p1 = Rl[bcur + 34]; p2 = Rl[bcur + 36]; p3 = Rl[bcur + 38]; \
            p4 = Rl[bcur + 16]; p5 = Rl[bcur + 18]; p6 = Rl[bcur + 20]; p7 = Rl[bcur + 22]; \
            pq0 = yrow4[8 * (s + 1) + 2 * g]; pq1 = yrow4[8 * (s + 1) + 2 * g + 1]; \
        } \
        MF(0, S0) MF(1, S1) MF(2, S2) MF(3, S3) MF(4, S4) MF(5, S5) MF(6, S6) MF(7, S7) \
    } }

    for (int sb = 1; sb < nsteps; sb += 4) {
        STEPP(0, 6, 7, 0, 1, 2, 3, 4, 5)
        STEPP(1, 4, 5, 6, 7, 0, 1, 2, 3)
        STEPP(2, 2, 3, 4, 5, 6, 7, 0, 1)
        STEPP(3, 0, 1, 2, 3, 4, 5, 6, 7)
    }
#undef STEPP
#undef MF
#undef PACKAV
#undef LOADF

    // ---- epilogue: out = acc + D*y ----
    const float D0 = Dp[0];
#pragma unroll
    for (int ti = 0; ti < 8; ++ti) {
        int tcol = t0 + 16 * ti + n;
#pragma unroll
        for (int r = 0; r < 4; ++r) {
            int dr = d0w + 4 * g + r;
            size_t ix = (size_t)dr * L_ + tcol;
            out[ix] = acc[ti][r] + D0 * y[ix];
        }
    }
}

// ---------------- host ----------------

extern "C" void kernel_launch(void* const* d_in, const int* in_sizes, int n_in,
                              void* d_out, int out_size, void* d_ws, size_t ws_size,
                              hipStream_t stream) {
    const float* y  = (const float*)d_in[0];
    const float* A  = (const float*)d_in[1];
    const float* Bv = (const float*)d_in[2];
    const float* Cv = (const float*)d_in[3];
    const float* Dp = (const float*)d_in[4];
    float* out = (float*)d_out;
    float* w = (float*)d_ws;

    float* W  = w;            // 64 x 256
    float* V  = w + 16384;    // 256 x 64
    float* Kf = w + 32768;    // 4096

    k_kry<<<dim3(2), dim3(256), 0, stream>>>(A, Bv, Cv, W, V);
    k_g<<<dim3(2, 2), dim3(256), 0, stream>>>(W, V, Kf, 64, 64, 256, 64, 64, 1.0f, 0.0f);
    k_conv<<<dim3(32, 32), dim3(256), 0, stream>>>(Kf, y, Dp, out);

    (void)in_sizes; (void)n_in; (void)out_size; (void)ws_size;
}

// Round 4
// 118.935 us; speedup vs baseline: 9.2098x; 1.8073x over previous
//
#include <hip/hip_runtime.h>

#define N_ 256
#define L_ 4096
#define DM_ 2048
#define STEPF (1.0f / 4096.0f)
#define NW 22   // W-side Taylor terms: ||0.984*A||~2.2 -> 2.2^22/22! ~ 3e-14
#define NV 6    // V-side Taylor terms: ||63*step*A||~0.034 -> 0.034^6/6! ~ 2e-12

typedef short bf16x8 __attribute__((ext_vector_type(8)));
typedef float f32x4 __attribute__((ext_vector_type(4)));
typedef unsigned int uint32;

__device__ __forceinline__ uint32 bf16rne(float f) {
    uint32 u = __builtin_bit_cast(uint32, f);
    return (u + 0x7FFFu + ((u >> 16) & 1u)) >> 16;
}
__device__ __forceinline__ uint32 pk2(float lo, float hi) {  // truncate-pack 2 f32 -> 2 bf16
    return (__builtin_bit_cast(uint32, hi) & 0xFFFF0000u) | (__builtin_bit_cast(uint32, lo) >> 16);
}
__device__ __forceinline__ float rdlane(float v, int l) {
    return __builtin_bit_cast(float, __builtin_amdgcn_readlane(__builtin_bit_cast(int, v), l));
}

// ---------------- Phase 1a: Krylov build of W (64x256) and V (256x64) ----------------
// S := ln(Abar) = step*A + O(M^3).  W[q,:] = C exp(64q S) = sum_n vt_n (q/63)^n,
// vt_n = C (4032 S)^n/n!.  V[:,r] = exp(r S) Bbar = sum_n ut_n (r/63)^n.
// 1024 threads: thread (seg=tid>>8, j=tid&255) holds 64-elem A-strip in VGPRs;
// v broadcast via readlane (VALU-only inner product, no LDS broadcast traffic).
__global__ __launch_bounds__(1024) void k_kry(const float* __restrict__ Araw,
                                              const float* __restrict__ Bv,
                                              const float* __restrict__ Cv,
                                              float* __restrict__ W,
                                              float* __restrict__ V) {
    __shared__ float kry[NW][256];
    __shared__ float red[4][256];
    __shared__ float cur[256];
    const int tid = threadIdx.x;
    const int j = tid & 255, seg = tid >> 8, lane = tid & 63;

#define DOT64(S0, S1, VV) { \
    _Pragma("unroll") \
    for (int m = 0; m < 64; m += 2) { \
        S0 = fmaf(rdlane(VV, m), a[m], S0); \
        S1 = fmaf(rdlane(VV, m + 1), a[m + 1], S1); \
    } }

    if (blockIdx.x == 0) {
        // ---- W-chain: row-Krylov vt_n = vt_{n-1} * A * (WSC/n) ----
        float a[64];
#pragma unroll
        for (int m = 0; m < 64; ++m) a[m] = Araw[(64 * seg + m) * 256 + j];  // A[k][j]
        if (tid < 256) kry[0][tid] = Cv[tid];
        __syncthreads();
        const float WSC = 4032.0f / 4096.0f;
        for (int n = 1; n < NW; ++n) {
            float vv = kry[n - 1][64 * seg + lane];
            float s0 = 0.f, s1 = 0.f;
            DOT64(s0, s1, vv)
            red[seg][j] = s0 + s1;
            __syncthreads();
            if (tid < 256)
                kry[n][tid] = (red[0][tid] + red[1][tid] + red[2][tid] + red[3][tid]) * (WSC / (float)n);
            __syncthreads();
        }
        // Horner over q: thread (j,seg) does q = seg + 4u
        float kj[NW];
#pragma unroll
        for (int n = 0; n < NW; ++n) kj[n] = kry[n][j];
        for (int u = 0; u < 16; ++u) {
            int q = seg + 4 * u;
            float c = (float)q * (1.0f / 63.0f);
            float h = kj[NW - 1];
#pragma unroll
            for (int n = NW - 2; n >= 0; --n) h = fmaf(c, h, kj[n]);
            W[q * 256 + j] = h;
        }
    } else {
        // ---- V-chain: column-Krylov. Bbar via 3-term Neumann first. ----
        float a[64];
#pragma unroll
        for (int m = 0; m < 64; ++m) a[m] = Araw[j * 256 + 64 * seg + m];  // A[i][k]
        if (tid < 256) cur[tid] = Bv[tid];
        __syncthreads();
        const float ms = 0.5f * STEPF;
        for (int it = 0; it < 3; ++it) {
            float vv = cur[64 * seg + lane];
            float s0 = 0.f, s1 = 0.f;
            DOT64(s0, s1, vv)
            red[seg][j] = s0 + s1;
            __syncthreads();
            if (tid < 256)
                cur[tid] = fmaf(ms, red[0][tid] + red[1][tid] + red[2][tid] + red[3][tid], Bv[tid]);
            __syncthreads();
        }
        if (tid < 256) kry[0][tid] = STEPF * cur[tid];
        __syncthreads();
        const float VSC = 63.0f / 4096.0f;
        for (int n = 1; n < NV; ++n) {
            float vv = kry[n - 1][64 * seg + lane];
            float s0 = 0.f, s1 = 0.f;
            DOT64(s0, s1, vv)
            red[seg][j] = s0 + s1;
            __syncthreads();
            if (tid < 256)
                kry[n][tid] = (red[0][tid] + red[1][tid] + red[2][tid] + red[3][tid]) * (VSC / (float)n);
            __syncthreads();
        }
        float kj[NV];
#pragma unroll
        for (int n = 0; n < NV; ++n) kj[n] = kry[n][j];
        for (int u = 0; u < 16; ++u) {
            int r = seg + 4 * u;
            float c = (float)r * (1.0f / 63.0f);
            float h = kj[NV - 1];
#pragma unroll
            for (int n = NV - 2; n >= 0; --n) h = fmaf(c, h, kj[n]);
            V[j * 64 + r] = h;
        }
    }
#undef DOT64
}

// ---------------- Phase 1b: small GEMM Kf = W * V  (Kf[64q + r] = K[l]) ----------------
__global__ __launch_bounds__(256) void k_g(const float* __restrict__ A, const float* __restrict__ B,
                                           float* __restrict__ C, int Ma, int Nb,
                                           int lda, int ldb, int ldc, float alpha, float diagv) {
    int row0 = blockIdx.y * 32, col0 = blockIdx.x * 32;
    if (row0 >= Ma || col0 >= Nb) return;
    __shared__ float As[16][33], Bs[16][33];
    int tid = threadIdx.x;
    int tx = tid & 15, ty = tid >> 4;
    int e0 = tid * 2, e1 = e0 + 1;
    int ai0 = e0 >> 4, ak0 = e0 & 15, ai1 = e1 >> 4, ak1 = e1 & 15;
    int bj0 = e0 & 31, bk0 = e0 >> 5, bj1 = e1 & 31, bk1 = e1 >> 5;
    bool va0 = (row0 + ai0) < Ma, va1 = (row0 + ai1) < Ma;
    bool vb0 = (col0 + bj0) < Nb, vb1 = (col0 + bj1) < Nb;
    float a0p = va0 ? A[(row0 + ai0) * lda + ak0] : 0.f;
    float a1p = va1 ? A[(row0 + ai1) * lda + ak1] : 0.f;
    float b0p = vb0 ? B[bk0 * ldb + col0 + bj0] : 0.f;
    float b1p = vb1 ? B[bk1 * ldb + col0 + bj1] : 0.f;
    float acc00 = 0.f, acc01 = 0.f, acc10 = 0.f, acc11 = 0.f;
    for (int kk = 0; kk < 256; kk += 16) {
        As[ak0][ai0] = a0p; As[ak1][ai1] = a1p;
        Bs[bk0][bj0] = b0p; Bs[bk1][bj1] = b1p;
        __syncthreads();
        if (kk + 16 < 256) {
            a0p = va0 ? A[(row0 + ai0) * lda + kk + 16 + ak0] : 0.f;
            a1p = va1 ? A[(row0 + ai1) * lda + kk + 16 + ak1] : 0.f;
            b0p = vb0 ? B[(bk0 + kk + 16) * ldb + col0 + bj0] : 0.f;
            b1p = vb1 ? B[(bk1 + kk + 16) * ldb + col0 + bj1] : 0.f;
        }
#pragma unroll
        for (int k = 0; k < 16; ++k) {
            float a0 = As[k][ty * 2], a1 = As[k][ty * 2 + 1];
            float b0 = Bs[k][tx * 2], b1 = Bs[k][tx * 2 + 1];
            acc00 = fmaf(a0, b0, acc00); acc01 = fmaf(a0, b1, acc01);
            acc10 = fmaf(a1, b0, acc10); acc11 = fmaf(a1, b1, acc11);
        }
        __syncthreads();
    }
    float accs[2][2] = {{acc00, acc01}, {acc10, acc11}};
#pragma unroll
    for (int i = 0; i < 2; ++i) {
        int r = row0 + ty * 2 + i;
        if (r < Ma)
#pragma unroll
            for (int jj = 0; jj < 2; ++jj) {
                int c = col0 + tx * 2 + jj;
                if (c < Nb) {
                    float v = alpha * accs[i][jj];
                    if (r == c) v += diagv;
                    C[r * ldc + c] = v;
                }
            }
    }
}

// ---------------- Phase 2: MFMA causal conv, software-pipelined ----------------
// Out[d,t] = sum_j y[d,j] K[t-j].  A-frag = y(bf16), B-frag = Toeplitz K from
// overlapping-quad LDS: Rq[i] = rev[i..i+3] (uint2, 8B aligned for any i) ->
// one frag = 2x ds_read_b64 (was 4x stride-2 b32). 1-step-ahead prefetch.
__global__ __launch_bounds__(256, 4) void k_conv(const float* __restrict__ Kf,
                                                 const float* __restrict__ y,
                                                 const float* __restrict__ Dp,
                                                 float* __restrict__ out) {
    __shared__ uint2 Rq[4352];
    const int tid = threadIdx.x;
#pragma unroll
    for (int i = 0; i < 17; ++i) {   // Rq[idx] = rev[idx..idx+3], rev[i] = K[4095-i] (0 OOB)
        int idx = i * 256 + tid;
        int a = 4095 - idx;
        uint32 e0 = (a >= 0) ? bf16rne(Kf[a]) : 0u;
        uint32 e1 = (a >= 1) ? bf16rne(Kf[a - 1]) : 0u;
        uint32 e2 = (a >= 2) ? bf16rne(Kf[a - 2]) : 0u;
        uint32 e3 = (a >= 3) ? bf16rne(Kf[a - 3]) : 0u;
        uint2 v; v.x = e0 | (e1 << 16); v.y = e2 | (e3 << 16);
        Rq[idx] = v;
    }
    __syncthreads();

    const int w = tid >> 6, lane = tid & 63;
    const int n = lane & 15, g = lane >> 4;
    const int t0 = (31 - (int)blockIdx.y) * 128;      // t-reversed: heavy blocks first
    const int d0w = (int)blockIdx.x * 64 + w * 16;
    const int d = d0w + n;
    const int nsteps = (t0 >> 5) + 4;
    const float4* __restrict__ yrow4 = (const float4*)(y + (size_t)d * L_);
    int base0 = 4095 - t0 - n + 8 * g;

    f32x4 acc[8];
#pragma unroll
    for (int i = 0; i < 8; ++i) acc[i] = (f32x4){0.f, 0.f, 0.f, 0.f};
    bf16x8 fr[8], av;
    uint2 pa0, pa1, pb0, pb1;
    float4 pq0, pq1;

#define LOADF(SL, I0) { \
    uint2 u0 = Rq[(I0)]; uint2 u1 = Rq[(I0) + 4]; \
    uint4 uu; uu.x = u0.x; uu.y = u0.y; uu.z = u1.x; uu.w = u1.y; \
    fr[SL] = __builtin_bit_cast(bf16x8, uu); }
#define PACKAV(Q0, Q1) { \
    uint4 ua; ua.x = pk2((Q0).x, (Q0).y); ua.y = pk2((Q0).z, (Q0).w); \
    ua.z = pk2((Q1).x, (Q1).y); ua.w = pk2((Q1).z, (Q1).w); \
    av = __builtin_bit_cast(bf16x8, ua); }
#define MF(TI, SL) acc[TI] = __builtin_amdgcn_mfma_f32_16x16x32_bf16(av, fr[SL], acc[TI], 0, 0, 0);

    // ---- prologue: step 0 + prefetch step 1 ----
    { float4 q0 = yrow4[2 * g], q1 = yrow4[2 * g + 1]; PACKAV(q0, q1); }
    LOADF(0, base0)       LOADF(1, base0 - 16)  LOADF(2, base0 - 32)  LOADF(3, base0 - 48)
    LOADF(4, base0 - 64)  LOADF(5, base0 - 80)  LOADF(6, base0 - 96)  LOADF(7, base0 - 112)
    pa0 = Rq[base0 + 32]; pa1 = Rq[base0 + 36];
    pb0 = Rq[base0 + 16]; pb1 = Rq[base0 + 20];
    pq0 = yrow4[8 + 2 * g]; pq1 = yrow4[8 + 2 * g + 1];
    MF(0, 0) MF(1, 1) MF(2, 2) MF(3, 3) MF(4, 4) MF(5, 5) MF(6, 6) MF(7, 7)

    int bcur = base0;

#define STEPP(I, S0, S1, S2, S3, S4, S5, S6, S7) { \
    const int s = sb + (I); \
    if (s < nsteps) { \
        { uint4 u0; u0.x = pa0.x; u0.y = pa0.y; u0.z = pa1.x; u0.w = pa1.y; fr[S0] = __builtin_bit_cast(bf16x8, u0); } \
        { uint4 u1; u1.x = pb0.x; u1.y = pb0.y; u1.z = pb1.x; u1.w = pb1.y; fr[S1] = __builtin_bit_cast(bf16x8, u1); } \
        PACKAV(pq0, pq1); \
        bcur += 32; \
        if (s + 1 < nsteps) { \
            pa0 = Rq[bcur + 32]; pa1 = Rq[bcur + 36]; \
            pb0 = Rq[bcur + 16]; pb1 = Rq[bcur + 20]; \
            pq0 = yrow4[8 * (s + 1) + 2 * g]; pq1 = yrow4[8 * (s + 1) + 2 * g + 1]; \
        } \
        MF(0, S0) MF(1, S1) MF(2, S2) MF(3, S3) MF(4, S4) MF(5, S5) MF(6, S6) MF(7, S7) \
    } }

    for (int sb = 1; sb < nsteps; sb += 4) {
        STEPP(0, 6, 7, 0, 1, 2, 3, 4, 5)
        STEPP(1, 4, 5, 6, 7, 0, 1, 2, 3)
        STEPP(2, 2, 3, 4, 5, 6, 7, 0, 1)
        STEPP(3, 0, 1, 2, 3, 4, 5, 6, 7)
    }
#undef STEPP
#undef MF
#undef PACKAV
#undef LOADF

    // ---- epilogue: out = acc + D*y ----
    const float D0 = Dp[0];
#pragma unroll
    for (int ti = 0; ti < 8; ++ti) {
        int tcol = t0 + 16 * ti + n;
#pragma unroll
        for (int r = 0; r < 4; ++r) {
            int dr = d0w + 4 * g + r;
            size_t ix = (size_t)dr * L_ + tcol;
            out[ix] = acc[ti][r] + D0 * y[ix];
        }
    }
}

// ---------------- host ----------------

extern "C" void kernel_launch(void* const* d_in, const int* in_sizes, int n_in,
                              void* d_out, int out_size, void* d_ws, size_t ws_size,
                              hipStream_t stream) {
    const float* y  = (const float*)d_in[0];
    const float* A  = (const float*)d_in[1];
    const float* Bv = (const float*)d_in[2];
    const float* Cv = (const float*)d_in[3];
    const float* Dp = (const float*)d_in[4];
    float* out = (float*)d_out;
    float* w = (float*)d_ws;

    float* W  = w;            // 64 x 256
    float* V  = w + 16384;    // 256 x 64
    float* Kf = w + 32768;    // 4096

    k_kry<<<dim3(2), dim3(1024), 0, stream>>>(A, Bv, Cv, W, V);
    k_g<<<dim3(2, 2), dim3(256), 0, stream>>>(W, V, Kf, 64, 64, 256, 64, 64, 1.0f, 0.0f);
    k_conv<<<dim3(32, 32), dim3(256), 0, stream>>>(Kf, y, Dp, out);

    (void)in_sizes; (void)n_in; (void)out_size; (void)ws_size;
}

// Round 5
// 103.418 us; speedup vs baseline: 10.5917x; 1.1500x over previous
//
#include <hip/hip_runtime.h>

#define N_ 256
#define L_ 4096
#define DM_ 2048
#define STEPF (1.0f / 4096.0f)
#define NW 22   // W-side Taylor terms: ||0.984*A||~2.2 -> 2.2^22/22! ~ 3e-14
#define NV 6    // V-side Taylor terms: ||63*step*A||~0.034 -> 0.034^6/6! ~ 2e-12
#define RQN 4608

typedef short bf16x8 __attribute__((ext_vector_type(8)));
typedef float f32x4 __attribute__((ext_vector_type(4)));
typedef unsigned int uint32;

__device__ __forceinline__ uint32 bf16rne(float f) {
    uint32 u = __builtin_bit_cast(uint32, f);
    return (u + 0x7FFFu + ((u >> 16) & 1u)) >> 16;
}
__device__ __forceinline__ uint32 pk2(float lo, float hi) {  // truncate-pack 2 f32 -> 2 bf16
    return (__builtin_bit_cast(uint32, hi) & 0xFFFF0000u) | (__builtin_bit_cast(uint32, lo) >> 16);
}
__device__ __forceinline__ float rdlane(float v, int l) {
    return __builtin_bit_cast(float, __builtin_amdgcn_readlane(__builtin_bit_cast(int, v), l));
}

// ---------------- Phase 1a: Krylov build of W (64x256) and V (256x64) ----------------
// S := ln(Abar) = step*A + O(M^3).  W[q,:] = C exp(64q S) = sum_n vt_n (q/63)^n,
// vt_n = C (4032 S)^n/n!.  V[:,r] = exp(r S) Bbar = sum_n ut_n (r/63)^n.
__global__ __launch_bounds__(1024) void k_kry(const float* __restrict__ Araw,
                                              const float* __restrict__ Bv,
                                              const float* __restrict__ Cv,
                                              float* __restrict__ W,
                                              float* __restrict__ V) {
    __shared__ float kry[NW][256];
    __shared__ float red[4][256];
    __shared__ float cur[256];
    const int tid = threadIdx.x;
    const int j = tid & 255, seg = tid >> 8, lane = tid & 63;

#define DOT64(S0, S1, VV) { \
    _Pragma("unroll") \
    for (int m = 0; m < 64; m += 2) { \
        S0 = fmaf(rdlane(VV, m), a[m], S0); \
        S1 = fmaf(rdlane(VV, m + 1), a[m + 1], S1); \
    } }

    if (blockIdx.x == 0) {
        // ---- W-chain: row-Krylov vt_n = vt_{n-1} * A * (WSC/n) ----
        float a[64];
#pragma unroll
        for (int m = 0; m < 64; ++m) a[m] = Araw[(64 * seg + m) * 256 + j];  // A[k][j]
        if (tid < 256) kry[0][tid] = Cv[tid];
        __syncthreads();
        const float WSC = 4032.0f / 4096.0f;
        for (int n = 1; n < NW; ++n) {
            float vv = kry[n - 1][64 * seg + lane];
            float s0 = 0.f, s1 = 0.f;
            DOT64(s0, s1, vv)
            red[seg][j] = s0 + s1;
            __syncthreads();
            if (tid < 256)
                kry[n][tid] = (red[0][tid] + red[1][tid] + red[2][tid] + red[3][tid]) * (WSC / (float)n);
            __syncthreads();
        }
        float kj[NW];
#pragma unroll
        for (int n = 0; n < NW; ++n) kj[n] = kry[n][j];
        for (int u = 0; u < 16; ++u) {
            int q = seg + 4 * u;
            float c = (float)q * (1.0f / 63.0f);
            float h = kj[NW - 1];
#pragma unroll
            for (int n = NW - 2; n >= 0; --n) h = fmaf(c, h, kj[n]);
            W[q * 256 + j] = h;
        }
    } else {
        // ---- V-chain: column-Krylov. Bbar via 3-term Neumann first. ----
        float a[64];
#pragma unroll
        for (int m = 0; m < 64; ++m) a[m] = Araw[j * 256 + 64 * seg + m];  // A[i][k]
        if (tid < 256) cur[tid] = Bv[tid];
        __syncthreads();
        const float ms = 0.5f * STEPF;
        for (int it = 0; it < 3; ++it) {
            float vv = cur[64 * seg + lane];
            float s0 = 0.f, s1 = 0.f;
            DOT64(s0, s1, vv)
            red[seg][j] = s0 + s1;
            __syncthreads();
            if (tid < 256)
                cur[tid] = fmaf(ms, red[0][tid] + red[1][tid] + red[2][tid] + red[3][tid], Bv[tid]);
            __syncthreads();
        }
        if (tid < 256) kry[0][tid] = STEPF * cur[tid];
        __syncthreads();
        const float VSC = 63.0f / 4096.0f;
        for (int n = 1; n < NV; ++n) {
            float vv = kry[n - 1][64 * seg + lane];
            float s0 = 0.f, s1 = 0.f;
            DOT64(s0, s1, vv)
            red[seg][j] = s0 + s1;
            __syncthreads();
            if (tid < 256)
                kry[n][tid] = (red[0][tid] + red[1][tid] + red[2][tid] + red[3][tid]) * (VSC / (float)n);
            __syncthreads();
        }
        float kj[NV];
#pragma unroll
        for (int n = 0; n < NV; ++n) kj[n] = kry[n][j];
        for (int u = 0; u < 16; ++u) {
            int r = seg + 4 * u;
            float c = (float)r * (1.0f / 63.0f);
            float h = kj[NV - 1];
#pragma unroll
            for (int n = NV - 2; n >= 0; --n) h = fmaf(c, h, kj[n]);
            V[j * 64 + r] = h;
        }
    }
#undef DOT64
}

// ---------------- Phase 1b: small GEMM Kf = W * V  (Kf[64q + r] = K[l]) ----------------
__global__ __launch_bounds__(256) void k_g(const float* __restrict__ A, const float* __restrict__ B,
                                           float* __restrict__ C, int Ma, int Nb,
                                           int lda, int ldb, int ldc, float alpha, float diagv) {
    int row0 = blockIdx.y * 32, col0 = blockIdx.x * 32;
    if (row0 >= Ma || col0 >= Nb) return;
    __shared__ float As[16][33], Bs[16][33];
    int tid = threadIdx.x;
    int tx = tid & 15, ty = tid >> 4;
    int e0 = tid * 2, e1 = e0 + 1;
    int ai0 = e0 >> 4, ak0 = e0 & 15, ai1 = e1 >> 4, ak1 = e1 & 15;
    int bj0 = e0 & 31, bk0 = e0 >> 5, bj1 = e1 & 31, bk1 = e1 >> 5;
    bool va0 = (row0 + ai0) < Ma, va1 = (row0 + ai1) < Ma;
    bool vb0 = (col0 + bj0) < Nb, vb1 = (col0 + bj1) < Nb;
    float a0p = va0 ? A[(row0 + ai0) * lda + ak0] : 0.f;
    float a1p = va1 ? A[(row0 + ai1) * lda + ak1] : 0.f;
    float b0p = vb0 ? B[bk0 * ldb + col0 + bj0] : 0.f;
    float b1p = vb1 ? B[bk1 * ldb + col0 + bj1] : 0.f;
    float acc00 = 0.f, acc01 = 0.f, acc10 = 0.f, acc11 = 0.f;
    for (int kk = 0; kk < 256; kk += 16) {
        As[ak0][ai0] = a0p; As[ak1][ai1] = a1p;
        Bs[bk0][bj0] = b0p; Bs[bk1][bj1] = b1p;
        __syncthreads();
        if (kk + 16 < 256) {
            a0p = va0 ? A[(row0 + ai0) * lda + kk + 16 + ak0] : 0.f;
            a1p = va1 ? A[(row0 + ai1) * lda + kk + 16 + ak1] : 0.f;
            b0p = vb0 ? B[(bk0 + kk + 16) * ldb + col0 + bj0] : 0.f;
            b1p = vb1 ? B[(bk1 + kk + 16) * ldb + col0 + bj1] : 0.f;
        }
#pragma unroll
        for (int k = 0; k < 16; ++k) {
            float a0 = As[k][ty * 2], a1 = As[k][ty * 2 + 1];
            float b0 = Bs[k][tx * 2], b1 = Bs[k][tx * 2 + 1];
            acc00 = fmaf(a0, b0, acc00); acc01 = fmaf(a0, b1, acc01);
            acc10 = fmaf(a1, b0, acc10); acc11 = fmaf(a1, b1, acc11);
        }
        __syncthreads();
    }
    float accs[2][2] = {{acc00, acc01}, {acc10, acc11}};
#pragma unroll
    for (int i = 0; i < 2; ++i) {
        int r = row0 + ty * 2 + i;
        if (r < Ma)
#pragma unroll
            for (int jj = 0; jj < 2; ++jj) {
                int c = col0 + tx * 2 + jj;
                if (c < Nb) {
                    float v = alpha * accs[i][jj];
                    if (r == c) v += diagv;
                    C[r * ldc + c] = v;
                }
            }
    }
}

// ---------------- Phase 2: MFMA causal conv, T=16 t-tiles/wave ----------------
// Out[d,t] = sum_j y[d,j] K[t-j].  Per step: only 2 NEW K-frags (rotation
// frag(ti,s+1)==frag(ti-2,s)) feed 16 MFMAs -> LDS reads/MFMA halved vs T=8.
// Slot map: slot(ti,s) = (ti-2s) mod 16, unrolled over full period 8.
__global__ __launch_bounds__(256, 2) void k_conv(const float* __restrict__ Kf,
                                                 const float* __restrict__ y,
                                                 const float* __restrict__ Dp,
                                                 float* __restrict__ out) {
    __shared__ uint2 Rq[RQN];
    const int tid = threadIdx.x;
#pragma unroll
    for (int i = 0; i < RQN / 256; ++i) {  // Rq[idx] = rev[idx..idx+3], rev[i]=K[4095-i] (0 OOB)
        int idx = i * 256 + tid;
        int a = 4095 - idx;
        uint32 e0 = (a >= 0) ? bf16rne(Kf[a]) : 0u;
        uint32 e1 = (a >= 1) ? bf16rne(Kf[a - 1]) : 0u;
        uint32 e2 = (a >= 2) ? bf16rne(Kf[a - 2]) : 0u;
        uint32 e3 = (a >= 3) ? bf16rne(Kf[a - 3]) : 0u;
        uint2 v; v.x = e0 | (e1 << 16); v.y = e2 | (e3 << 16);
        Rq[idx] = v;
    }
    __syncthreads();

    const int w = tid >> 6, lane = tid & 63;
    const int n = lane & 15, g = lane >> 4;
    const int t0 = (15 - (int)blockIdx.y) * 256;      // t-reversed: heavy blocks first
    const int d0w = (int)blockIdx.x * 64 + w * 16;    // same-d t-blocks land on same XCD
    const int d = d0w + n;
    const int nsteps = (t0 >> 5) + 8;
    const float4* __restrict__ yrow4 = (const float4*)(y + (size_t)d * L_);
    int base0 = 4095 - t0 - n + 8 * g;

    f32x4 acc[16];
#pragma unroll
    for (int i = 0; i < 16; ++i) acc[i] = (f32x4){0.f, 0.f, 0.f, 0.f};
    bf16x8 fr[16], av;
    uint2 pa0, pa1, pb0, pb1;
    float4 q0a, q0b, q1a, q1b;   // y prefetch, 2 steps deep

#define LOADF(SL, I0) { \
    uint2 u0 = Rq[(I0)]; uint2 u1 = Rq[(I0) + 4]; \
    uint4 uu; uu.x = u0.x; uu.y = u0.y; uu.z = u1.x; uu.w = u1.y; \
    fr[SL] = __builtin_bit_cast(bf16x8, uu); }
#define PACKAV(Q0, Q1) { \
    uint4 ua; ua.x = pk2((Q0).x, (Q0).y); ua.y = pk2((Q0).z, (Q0).w); \
    ua.z = pk2((Q1).x, (Q1).y); ua.w = pk2((Q1).z, (Q1).w); \
    av = __builtin_bit_cast(bf16x8, ua); }
#define MF(TI, SL) acc[TI] = __builtin_amdgcn_mfma_f32_16x16x32_bf16(av, fr[SL], acc[TI], 0, 0, 0);
#define MFALL(S0,S1,S2,S3,S4,S5,S6,S7,S8,S9,S10,S11,S12,S13,S14,S15) \
    MF(0,S0) MF(1,S1) MF(2,S2) MF(3,S3) MF(4,S4) MF(5,S5) MF(6,S6) MF(7,S7) \
    MF(8,S8) MF(9,S9) MF(10,S10) MF(11,S11) MF(12,S12) MF(13,S13) MF(14,S14) MF(15,S15)

    // ---- prologue: step 0 (slots = ti), prefetch K for s=1, y for s=1,2 ----
    { float4 q0 = yrow4[2 * g], q1 = yrow4[2 * g + 1]; PACKAV(q0, q1); }
#pragma unroll
    for (int ti = 0; ti < 16; ++ti) LOADF(ti, base0 - 16 * ti)
    pa0 = Rq[base0 + 32]; pa1 = Rq[base0 + 36];
    pb0 = Rq[base0 + 16]; pb1 = Rq[base0 + 20];
    q0a = yrow4[8 + 2 * g];  q0b = yrow4[8 + 2 * g + 1];
    q1a = yrow4[16 + 2 * g]; q1b = yrow4[16 + 2 * g + 1];
    MFALL(0,1,2,3,4,5,6,7,8,9,10,11,12,13,14,15)

    int bcur = base0;

#define STEPP(I, S0,S1,S2,S3,S4,S5,S6,S7,S8,S9,S10,S11,S12,S13,S14,S15) { \
    const int s = sb + (I); \
    if (s < nsteps) { \
        { uint4 u0; u0.x = pa0.x; u0.y = pa0.y; u0.z = pa1.x; u0.w = pa1.y; fr[S0] = __builtin_bit_cast(bf16x8, u0); } \
        { uint4 u1; u1.x = pb0.x; u1.y = pb0.y; u1.z = pb1.x; u1.w = pb1.y; fr[S1] = __builtin_bit_cast(bf16x8, u1); } \
        PACKAV(q0a, q0b); \
        q0a = q1a; q0b = q1b; \
        bcur += 32; \
        if (s + 1 < nsteps) { \
            pa0 = Rq[bcur + 32]; pa1 = Rq[bcur + 36]; \
            pb0 = Rq[bcur + 16]; pb1 = Rq[bcur + 20]; \
        } \
        if (s + 2 < nsteps) { \
            q1a = yrow4[8 * (s + 2) + 2 * g]; q1b = yrow4[8 * (s + 2) + 2 * g + 1]; \
        } \
        MFALL(S0,S1,S2,S3,S4,S5,S6,S7,S8,S9,S10,S11,S12,S13,S14,S15) \
    } }

    for (int sb = 1; sb < nsteps; sb += 8) {
        STEPP(0, 14,15,0,1,2,3,4,5,6,7,8,9,10,11,12,13)
        STEPP(1, 12,13,14,15,0,1,2,3,4,5,6,7,8,9,10,11)
        STEPP(2, 10,11,12,13,14,15,0,1,2,3,4,5,6,7,8,9)
        STEPP(3, 8,9,10,11,12,13,14,15,0,1,2,3,4,5,6,7)
        STEPP(4, 6,7,8,9,10,11,12,13,14,15,0,1,2,3,4,5)
        STEPP(5, 4,5,6,7,8,9,10,11,12,13,14,15,0,1,2,3)
        STEPP(6, 2,3,4,5,6,7,8,9,10,11,12,13,14,15,0,1)
        STEPP(7, 0,1,2,3,4,5,6,7,8,9,10,11,12,13,14,15)
    }
#undef STEPP
#undef MFALL
#undef MF
#undef PACKAV
#undef LOADF

    // ---- epilogue: out = acc + D*y ----
    const float D0 = Dp[0];
#pragma unroll
    for (int ti = 0; ti < 16; ++ti) {
        int tcol = t0 + 16 * ti + n;
#pragma unroll
        for (int r = 0; r < 4; ++r) {
            int dr = d0w + 4 * g + r;
            size_t ix = (size_t)dr * L_ + tcol;
            out[ix] = acc[ti][r] + D0 * y[ix];
        }
    }
}

// ---------------- host ----------------

extern "C" void kernel_launch(void* const* d_in, const int* in_sizes, int n_in,
                              void* d_out, int out_size, void* d_ws, size_t ws_size,
                              hipStream_t stream) {
    const float* y  = (const float*)d_in[0];
    const float* A  = (const float*)d_in[1];
    const float* Bv = (const float*)d_in[2];
    const float* Cv = (const float*)d_in[3];
    const float* Dp = (const float*)d_in[4];
    float* out = (float*)d_out;
    float* w = (float*)d_ws;

    float* W  = w;            // 64 x 256
    float* V  = w + 16384;    // 256 x 64
    float* Kf = w + 32768;    // 4096

    k_kry<<<dim3(2), dim3(1024), 0, stream>>>(A, Bv, Cv, W, V);
    k_g<<<dim3(2, 2), dim3(256), 0, stream>>>(W, V, Kf, 64, 64, 256, 64, 64, 1.0f, 0.0f);
    k_conv<<<dim3(32, 16), dim3(256), 0, stream>>>(Kf, y, Dp, out);

    (void)in_sizes; (void)n_in; (void)out_size; (void)ws_size;
}